// Round 10
// baseline (360.242 us; speedup 1.0000x reference)
//
#include <hip/hip_runtime.h>

#define N_NODES 100000
#define N_EDGES 1250000
#define D 64
#define TR_BLOCKS ((N_NODES + 63) / 64)   // 1563
#define SC_BLOCKS 2048                    // 8 blocks/CU x 4 waves = 32 waves/CU
#define UNROLL 4

// ---------------------------------------------------------------------------
// Workspace layout (bytes):
//   g16 @ 0 : N*64 bf16 = 12,800,000  (bf16(h @ W^T))
// The bin/packed/gcursor machinery is GONE: aggregation now happens via
// direct fp32 atomicAdd into out (6.4M distinct addresses, ~12.5 adds each
// -- NOT R7's 1563 same-address counters, which was the actual disaster).
// ---------------------------------------------------------------------------

typedef __attribute__((ext_vector_type(8))) short bf16x8;   // MFMA A/B frag (4 VGPR)
typedef __attribute__((ext_vector_type(4))) float f32x4;    // MFMA C/D frag

__device__ __forceinline__ unsigned bf16_rne(float x) {
    unsigned u = __float_as_uint(x);
    return (u + 0x7FFFu + ((u >> 16) & 1u)) >> 16;
}
__device__ __forceinline__ float bf16_to_f(unsigned short v) {
    return __uint_as_float(((unsigned)v) << 16);
}

// Split fp32 -> bf16 hi + bf16 lo with x ~= hi + lo (residual ~2^-18 rel).
__device__ __forceinline__ void bf16_split(float x, short& hi, short& lo) {
    unsigned hb = bf16_rne(x);
    float fh = __uint_as_float(hb << 16);
    hi = (short)hb;
    lo = (short)bf16_rne(x - fh);
}

// g16 = bf16(h @ W^T) via MFMA split-bf16 (R6's proven form), plus
// bias-initialization of out for this block's 64 nodes (scatter kernel
// then accumulates on top). B fragments loaded/split per (nt,kk) so only
// 8 B-regs live at once. C/D layout (m89): col=lane&15, row=(lane>>4)*4+reg.
__global__ __launch_bounds__(256) void transform_kernel(const float* __restrict__ h,
                                                        const float* __restrict__ W,
                                                        unsigned short* __restrict__ g16,
                                                        const float* __restrict__ bias,
                                                        float* __restrict__ out) {
    __shared__ unsigned short sh[64 * D];   // 8 KB

    int t = threadIdx.x;
    int bx = blockIdx.x;
    int lane = t & 63;
    int w = t >> 6;
    int li = lane & 15;      // A row / B col within 16-tile
    int lg = lane >> 4;      // k-group (0..3), 8 contiguous k each
    int nodebase = bx * 64 + w * 16;

    int arow = nodebase + li;
    if (arow > N_NODES - 1) arow = N_NODES - 1;

    f32x4 acc[4];
#pragma unroll
    for (int nt = 0; nt < 4; ++nt) acc[nt] = (f32x4){0.f, 0.f, 0.f, 0.f};

#pragma unroll
    for (int kk = 0; kk < 2; ++kk) {
        const float* hp = h + (long)arow * D + kk * 32 + lg * 8;
        float4 h0 = *(const float4*)hp;
        float4 h1 = *(const float4*)(hp + 4);
        float av[8] = {h0.x, h0.y, h0.z, h0.w, h1.x, h1.y, h1.z, h1.w};
        bf16x8 ahi, alo;
#pragma unroll
        for (int q = 0; q < 8; ++q) { short a, b; bf16_split(av[q], a, b); ahi[q] = a; alo[q] = b; }

#pragma unroll
        for (int nt = 0; nt < 4; ++nt) {
            const float* wp = W + (nt * 16 + li) * D + kk * 32 + lg * 8;
            float4 w0 = *(const float4*)wp;
            float4 w1 = *(const float4*)(wp + 4);
            float bv[8] = {w0.x, w0.y, w0.z, w0.w, w1.x, w1.y, w1.z, w1.w};
            bf16x8 bhi, blo;
#pragma unroll
            for (int q = 0; q < 8; ++q) { short a, b; bf16_split(bv[q], a, b); bhi[q] = a; blo[q] = b; }

            acc[nt] = __builtin_amdgcn_mfma_f32_16x16x32_bf16(ahi, bhi, acc[nt], 0, 0, 0);
            acc[nt] = __builtin_amdgcn_mfma_f32_16x16x32_bf16(ahi, blo, acc[nt], 0, 0, 0);
            acc[nt] = __builtin_amdgcn_mfma_f32_16x16x32_bf16(alo, bhi, acc[nt], 0, 0, 0);
        }
    }

    // stage C in LDS (bf16), then coalesced uint4 flush
#pragma unroll
    for (int nt = 0; nt < 4; ++nt) {
#pragma unroll
        for (int r = 0; r < 4; ++r) {
            sh[(w * 16 + lg * 4 + r) * D + nt * 16 + li] = (unsigned short)bf16_rne(acc[nt][r]);
        }
    }

    // bias-init this block's out rows while the LDS barrier settles:
    // 64 nodes x 64 feats = 1024 float4, 4 per thread, coalesced.
    {
        const float4* b4 = (const float4*)bias;
        float4* o4 = (float4*)(out + (long)bx * 64 * D);
#pragma unroll
        for (int i = t; i < 1024; i += 256) {
            int n = bx * 64 + (i >> 4);
            if (n < N_NODES) o4[i] = b4[i & 15];
        }
    }
    __syncthreads();

    const uint4* s4 = (const uint4*)sh;
    uint4* g4 = (uint4*)(g16 + (long)bx * 64 * D);
#pragma unroll
    for (int i = t; i < 512; i += 256) {
        int n = bx * 64 + (i >> 3);
        if (n < N_NODES) g4[i] = s4[i];
    }
}

// Edge-parallel scatter-add: wave = one edge x 64 feature lanes; 4 edges
// in flight per wave (independent g16 row loads), then 4 fire-and-forget
// 256-B contiguous atomic bursts into out. No LDS, no barriers, ~20 VGPRs,
// grid-stride at 32 waves/CU. Distinct-address atomics (~12.5 adds per
// out-row over the whole kernel) -- the opposite regime from R7's
// same-address counter convoy.
__global__ __launch_bounds__(256) void scatter_kernel(const unsigned short* __restrict__ g16,
                                                      const int* __restrict__ src,
                                                      const int* __restrict__ dst,
                                                      const float* __restrict__ e,
                                                      float* __restrict__ out) {
    int lane = threadIdx.x & 63;
    int gw = (blockIdx.x * 256 + threadIdx.x) >> 6;    // global wave id
    const int nw = SC_BLOCKS * 4;                      // total waves

    for (int base = gw * UNROLL; base < N_EDGES; base += nw * UNROLL) {
        int i0 = base, i1 = base + 1, i2 = base + 2, i3 = base + 3;
        bool v1 = i1 < N_EDGES, v2 = i2 < N_EDGES, v3 = i3 < N_EDGES;

        // edge scalars (wave-uniform addresses -> broadcast loads)
        int s0 = src[i0];          int d0 = dst[i0];          float w0 = e[i0];
        int s1 = v1 ? src[i1] : 0; int d1 = v1 ? dst[i1] : 0; float w1 = v1 ? e[i1] : 0.f;
        int s2 = v2 ? src[i2] : 0; int d2 = v2 ? dst[i2] : 0; float w2 = v2 ? e[i2] : 0.f;
        int s3 = v3 ? src[i3] : 0; int d3 = v3 ? dst[i3] : 0; float w3 = v3 ? e[i3] : 0.f;

        // 4 independent coalesced 128-B g16 row loads in flight
        float g0 = bf16_to_f(g16[(long)s0 * D + lane]);
        float g1 = bf16_to_f(g16[(long)s1 * D + lane]);
        float g2 = bf16_to_f(g16[(long)s2 * D + lane]);
        float g3 = bf16_to_f(g16[(long)s3 * D + lane]);

        atomicAdd(&out[(long)d0 * D + lane], w0 * g0);
        if (v1) atomicAdd(&out[(long)d1 * D + lane], w1 * g1);
        if (v2) atomicAdd(&out[(long)d2 * D + lane], w2 * g2);
        if (v3) atomicAdd(&out[(long)d3 * D + lane], w3 * g3);
    }
}

// ---------------------------------------------------------------------------
extern "C" void kernel_launch(void* const* d_in, const int* in_sizes, int n_in,
                              void* d_out, int out_size, void* d_ws, size_t ws_size,
                              hipStream_t stream) {
    const float* h   = (const float*)d_in[0];
    const float* e   = (const float*)d_in[1];
    const int*   src = (const int*)d_in[2];
    const int*   dst = (const int*)d_in[3];
    const float* W   = (const float*)d_in[4];
    const float* b   = (const float*)d_in[5];
    float* out = (float*)d_out;

    char* ws = (char*)d_ws;
    unsigned short* g16 = (unsigned short*)ws;

    // 1) g16 = bf16(h @ W^T) + bias-init of out (MFMA split-bf16)
    transform_kernel<<<TR_BLOCKS, 256, 0, stream>>>(h, W, g16, b, out);

    // 2) direct edge-parallel atomic scatter-add (replaces bin+sort+gather)
    scatter_kernel<<<SC_BLOCKS, 256, 0, stream>>>(g16, src, dst, e, out);
}

// Round 11
// 158.131 us; speedup vs baseline: 2.2781x; 2.2781x over previous
//
#include <hip/hip_runtime.h>

#define N_NODES 100000
#define N_EDGES 1250000
#define D 64
#define BUCKET_BITS 6                  // 64 nodes / bucket
#define BUCKET_SZ 64
#define NBUCK 1563                     // ceil(100000/64)
#define CAP 1024                       // fixed bucket capacity (mean 800, sigma ~28; max~908)
#define EPT 16                         // edges per thread per pass in bin path
#define EPB (EPT * 256)                // 4096 edges per bin block
#define BIN_BLOCKS ((N_EDGES + EPB - 1) / EPB)   // 306
#define TR_BLOCKS ((N_NODES + 63) / 64)          // 1563
#define FUSED_BLOCKS (TR_BLOCKS + BIN_BLOCKS)    // 1869

// ---------------------------------------------------------------------------
// Workspace layout (bytes):
//   packed  @ 0          : NBUCK*CAP int2 = 12,804,096  (src|dlocal<<20, e)
//   gcursor @ 12,804,096 : NBUCK i32      =      6,252  (hipMemsetAsync zeroed)
//   g16     @ 12,810,368 : N*64 bf16      = 12,800,000  (bf16(h @ W^T))
// total ~= 25.6 MB
// ---------------------------------------------------------------------------

typedef __attribute__((ext_vector_type(8))) short bf16x8;   // MFMA A/B frag (4 VGPR)
typedef __attribute__((ext_vector_type(4))) float f32x4;    // MFMA C/D frag

__device__ __forceinline__ unsigned bf16_rne(float x) {
    unsigned u = __float_as_uint(x);
    return (u + 0x7FFFu + ((u >> 16) & 1u)) >> 16;
}
__device__ __forceinline__ float bf16_to_f(unsigned short v) {
    return __uint_as_float(((unsigned)v) << 16);
}

// Split fp32 -> bf16 hi + bf16 lo with x ~= hi + lo (residual ~2^-18 rel).
__device__ __forceinline__ void bf16_split(float x, short& hi, short& lo) {
    unsigned hb = bf16_rne(x);
    float fh = __uint_as_float(hb << 16);
    hi = (short)hb;
    lo = (short)bf16_rne(x - fh);
}

// Fused bin + transform, BIN BLOCKS FIRST (blockIdx 0..305), transform after.
// R5-R9 post-mortem: the fused kernel's invariant 44-56 us with 18% occupancy
// is a low-parallelism BIN TAIL (306 blocks ~= 1.2/CU straggling after 1563
// transform blocks drain; R9's EPT=32 halved bin blocks -> 77 us, confirming
// tail sensitivity to bin parallelism). Index-ordered dispatch starts bin
// first; transform fills in behind; the kernel tail is the wide transform
// phase. Bin = two-pass LDS histogram (register-light, no spill arrays --
// R6 lesson); R7/R10 lessons: aggregation must stay in LDS, never per-edge
// global atomics (R7 convoy) or fp32 out-atomics (R10 HBM write-through).
__global__ __launch_bounds__(256) void transform_bin_kernel(const float* __restrict__ h,
                                                            const float* __restrict__ W,
                                                            unsigned short* __restrict__ g16,
                                                            const int* __restrict__ src,
                                                            const int* __restrict__ dst,
                                                            const float* __restrict__ e,
                                                            int* __restrict__ gcursor,
                                                            int2* __restrict__ packed) {
    __shared__ __align__(16) char smem_raw[12544];  // union: sh 8KB | lhist+lcur 12.5KB

    int t = threadIdx.x;
    int bx = blockIdx.x;

    if (bx < BIN_BLOCKS) {
        // ================= bin path: two-pass, register-light =================
        int* lhist = (int*)smem_raw;               // NBUCK counts -> global bases
        int* lcur  = lhist + NBUCK;                // NBUCK local cursors
        int base = bx * EPB;

        for (int j = t; j < NBUCK; j += 256) { lhist[j] = 0; lcur[j] = 0; }
        __syncthreads();

        // pass 1: histogram dst buckets (no per-edge state kept)
#pragma unroll 8
        for (int j = 0; j < EPT; ++j) {
            int i = base + j * 256 + t;
            if (i < N_EDGES) atomicAdd(&lhist[dst[i] >> BUCKET_BITS], 1);
        }
        __syncthreads();

        // reserve contiguous global ranges: one atomic per nonzero bucket
        for (int x = t; x < NBUCK; x += 256) {
            int c = lhist[x];
            lhist[x] = (c > 0) ? atomicAdd(&gcursor[x], c) : 0;
        }
        __syncthreads();

        // pass 2: re-read edges, scatter to reserved positions
#pragma unroll 8
        for (int j = 0; j < EPT; ++j) {
            int i = base + j * 256 + t;
            if (i < N_EDGES) {
                int d = dst[i];
                int bk = d >> BUCKET_BITS;
                int pos = lhist[bk] + atomicAdd(&lcur[bk], 1);
                if (pos < CAP)
                    packed[bk * CAP + pos] = make_int2(src[i] | ((d & (BUCKET_SZ - 1)) << 20),
                                                       __float_as_int(e[i]));
            }
        }
    } else {
        // ================= transform path (R6 proven form) =================
        unsigned short* sh = (unsigned short*)smem_raw;
        int trb = bx - BIN_BLOCKS;                 // 0..TR_BLOCKS-1
        int lane = t & 63;
        int w = t >> 6;
        int li = lane & 15;      // A row / B col within 16-tile
        int lg = lane >> 4;      // k-group (0..3), 8 contiguous k each
        int nodebase = trb * 64 + w * 16;

        int arow = nodebase + li;
        if (arow > N_NODES - 1) arow = N_NODES - 1;

        f32x4 acc[4];
#pragma unroll
        for (int nt = 0; nt < 4; ++nt) acc[nt] = (f32x4){0.f, 0.f, 0.f, 0.f};

#pragma unroll
        for (int kk = 0; kk < 2; ++kk) {
            const float* hp = h + (long)arow * D + kk * 32 + lg * 8;
            float4 h0 = *(const float4*)hp;
            float4 h1 = *(const float4*)(hp + 4);
            float av[8] = {h0.x, h0.y, h0.z, h0.w, h1.x, h1.y, h1.z, h1.w};
            bf16x8 ahi, alo;
#pragma unroll
            for (int q = 0; q < 8; ++q) { short a, b; bf16_split(av[q], a, b); ahi[q] = a; alo[q] = b; }

#pragma unroll
            for (int nt = 0; nt < 4; ++nt) {
                const float* wp = W + (nt * 16 + li) * D + kk * 32 + lg * 8;
                float4 w0 = *(const float4*)wp;
                float4 w1 = *(const float4*)(wp + 4);
                float bv[8] = {w0.x, w0.y, w0.z, w0.w, w1.x, w1.y, w1.z, w1.w};
                bf16x8 bhi, blo;
#pragma unroll
                for (int q = 0; q < 8; ++q) { short a, b; bf16_split(bv[q], a, b); bhi[q] = a; blo[q] = b; }

                acc[nt] = __builtin_amdgcn_mfma_f32_16x16x32_bf16(ahi, bhi, acc[nt], 0, 0, 0);
                acc[nt] = __builtin_amdgcn_mfma_f32_16x16x32_bf16(ahi, blo, acc[nt], 0, 0, 0);
                acc[nt] = __builtin_amdgcn_mfma_f32_16x16x32_bf16(alo, bhi, acc[nt], 0, 0, 0);
            }
        }

        // C/D layout (m89): col = lane&15, row = (lane>>4)*4 + reg. Stage in LDS.
#pragma unroll
        for (int nt = 0; nt < 4; ++nt) {
#pragma unroll
            for (int r = 0; r < 4; ++r) {
                sh[(w * 16 + lg * 4 + r) * D + nt * 16 + li] = (unsigned short)bf16_rne(acc[nt][r]);
            }
        }
        __syncthreads();

        // coalesced flush: 512 uint4 per block, 2 per thread.
        const uint4* s4 = (const uint4*)sh;
        uint4* g4 = (uint4*)(g16 + (long)trb * 64 * D);
#pragma unroll
        for (int i = t; i < 512; i += 256) {
            int n = trb * 64 + (i >> 3);
            if (n < N_NODES) g4[i] = s4[i];
        }
    }
}

// Per-bucket gather, 512 threads = 8 waves x 8 nodes: counting-sort edges
// by node in LDS (single packed read, register-cached; wave-0 shuffle scan),
// then per-node 8-deep-unrolled register accumulation (R3 lesson: no
// per-edge LDS writes in the hot loop).
__global__ __launch_bounds__(512) void gather_bucket_kernel(const unsigned short* __restrict__ g16,
                                                            const int2* __restrict__ packed,
                                                            const int* __restrict__ gcursor,
                                                            const float* __restrict__ bias,
                                                            float* __restrict__ out) {
    __shared__ int2 eds[CAP];
    __shared__ int nhist[BUCKET_SZ];
    __shared__ int nbase[BUCKET_SZ];
    __shared__ int ncur[BUCKET_SZ];

    int t = threadIdx.x;
    int bk = blockIdx.x;
    int start = bk * CAP;
    int cnt = gcursor[bk];
    if (cnt > CAP) cnt = CAP;

    if (t < BUCKET_SZ) nhist[t] = 0;
    __syncthreads();

    // single packed read, cached in named registers (static indexing)
    int2 pa = make_int2(0, 0), pb = pa;
    bool va = t < cnt, vb = t + 512 < cnt;
    if (va) pa = packed[start + t];
    if (vb) pb = packed[start + t + 512];
    if (va) atomicAdd(&nhist[(pa.x >> 20) & (BUCKET_SZ - 1)], 1);
    if (vb) atomicAdd(&nhist[(pb.x >> 20) & (BUCKET_SZ - 1)], 1);
    __syncthreads();

    // wave-0 shuffle inclusive scan over 64 bins -> exclusive bases
    if (t < BUCKET_SZ) {
        int c = nhist[t];
        int v = c;
#pragma unroll
        for (int off = 1; off < BUCKET_SZ; off <<= 1) {
            int x = __shfl_up(v, off, 64);
            if (t >= off) v += x;
        }
        nbase[t] = v - c;
        ncur[t] = v - c;
    }
    __syncthreads();

    // scatter from registers into node-sorted LDS order
    if (va) { int dl = (pa.x >> 20) & (BUCKET_SZ - 1); eds[atomicAdd(&ncur[dl], 1)] = pa; }
    if (vb) { int dl = (pb.x >> 20) & (BUCKET_SZ - 1); eds[atomicAdd(&ncur[dl], 1)] = pb; }
    __syncthreads();

    // per-node gather: wave w handles nodes [w*8, w*8+8); lane = feature
    int w = t >> 6;
    int lane = t & 63;
    float bv = bias[lane];
    for (int jj = 0; jj < 8; ++jj) {
        int n = w * 8 + jj;
        int gn = bk * BUCKET_SZ + n;
        int s = nbase[n];
        int c = nhist[n];
        float acc = bv;
        int k = 0;
        for (; k + 8 <= c; k += 8) {           // 8 independent 128-B lines in flight
            int2 q0 = eds[s + k + 0], q1 = eds[s + k + 1];
            int2 q2 = eds[s + k + 2], q3 = eds[s + k + 3];
            int2 q4 = eds[s + k + 4], q5 = eds[s + k + 5];
            int2 q6 = eds[s + k + 6], q7 = eds[s + k + 7];
            float g0 = bf16_to_f(g16[(long)(q0.x & 0xFFFFF) * D + lane]);
            float g1 = bf16_to_f(g16[(long)(q1.x & 0xFFFFF) * D + lane]);
            float g2 = bf16_to_f(g16[(long)(q2.x & 0xFFFFF) * D + lane]);
            float g3 = bf16_to_f(g16[(long)(q3.x & 0xFFFFF) * D + lane]);
            float g4 = bf16_to_f(g16[(long)(q4.x & 0xFFFFF) * D + lane]);
            float g5 = bf16_to_f(g16[(long)(q5.x & 0xFFFFF) * D + lane]);
            float g6 = bf16_to_f(g16[(long)(q6.x & 0xFFFFF) * D + lane]);
            float g7 = bf16_to_f(g16[(long)(q7.x & 0xFFFFF) * D + lane]);
            acc += __int_as_float(q0.y) * g0;
            acc += __int_as_float(q1.y) * g1;
            acc += __int_as_float(q2.y) * g2;
            acc += __int_as_float(q3.y) * g3;
            acc += __int_as_float(q4.y) * g4;
            acc += __int_as_float(q5.y) * g5;
            acc += __int_as_float(q6.y) * g6;
            acc += __int_as_float(q7.y) * g7;
        }
        if (k + 4 <= c) {
            int2 q0 = eds[s + k + 0], q1 = eds[s + k + 1];
            int2 q2 = eds[s + k + 2], q3 = eds[s + k + 3];
            float g0 = bf16_to_f(g16[(long)(q0.x & 0xFFFFF) * D + lane]);
            float g1 = bf16_to_f(g16[(long)(q1.x & 0xFFFFF) * D + lane]);
            float g2 = bf16_to_f(g16[(long)(q2.x & 0xFFFFF) * D + lane]);
            float g3 = bf16_to_f(g16[(long)(q3.x & 0xFFFFF) * D + lane]);
            acc += __int_as_float(q0.y) * g0;
            acc += __int_as_float(q1.y) * g1;
            acc += __int_as_float(q2.y) * g2;
            acc += __int_as_float(q3.y) * g3;
            k += 4;
        }
        for (; k < c; ++k) {
            int2 q = eds[s + k];
            acc += __int_as_float(q.y) * bf16_to_f(g16[(long)(q.x & 0xFFFFF) * D + lane]);
        }
        if (gn < N_NODES) out[(long)gn * D + lane] = acc;
    }
}

// ---------------------------------------------------------------------------
extern "C" void kernel_launch(void* const* d_in, const int* in_sizes, int n_in,
                              void* d_out, int out_size, void* d_ws, size_t ws_size,
                              hipStream_t stream) {
    const float* h   = (const float*)d_in[0];
    const float* e   = (const float*)d_in[1];
    const int*   src = (const int*)d_in[2];
    const int*   dst = (const int*)d_in[3];
    const float* W   = (const float*)d_in[4];
    const float* b   = (const float*)d_in[5];
    float* out = (float*)d_out;

    char* ws = (char*)d_ws;
    int2*           packed  = (int2*)          (ws);
    int*            gcursor = (int*)           (ws + 12804096);
    unsigned short* g16     = (unsigned short*)(ws + 12810368);

    // 1) zero bucket cursors (workspace is poison-filled every iteration)
    hipMemsetAsync(gcursor, 0, NBUCK * sizeof(int), stream);

    // 2) fused: bin blocks FIRST (0..305), transform after -> bin overlaps
    //    the wide transform phase; kernel tail is transform, not bin
    transform_bin_kernel<<<FUSED_BLOCKS, 256, 0, stream>>>(h, W, g16, src, dst, e, gcursor, packed);

    // 3) per-bucket counting-sort gather + bias (8 waves x 8 nodes, MLP-8)
    gather_bucket_kernel<<<NBUCK, 512, 0, stream>>>(g16, packed, gcursor, b, out);
}